// Round 14
// baseline (106.330 us; speedup 1.0000x reference)
//
#include <hip/hip_runtime.h>
#include <math.h>

typedef float f32x4 __attribute__((ext_vector_type(4)));
typedef short bf16x8 __attribute__((ext_vector_type(8)));  // 8 bf16 in 4 VGPR

namespace {
constexpr int kB = 8, kL = 512, kD = 64, kS = 8;
// workspace layout (bytes)
constexpr size_t SCL_OFF = 0;                       // f32[4][8][8][512]   = 512 KB
constexpr size_t U_OFF   = 524288;                  // bf16[8][8][512][64] =   4 MB  (Ut[b][s][j][d])
}

__device__ __forceinline__ unsigned short f2bf(float f) {      // RNE float->bf16
    unsigned u = __float_as_uint(f);
    u += 0x7FFFu + ((u >> 16) & 1u);
    return (unsigned short)(u >> 16);
}
__device__ __forceinline__ unsigned pk2(float lo, float hi) {
    return (unsigned)f2bf(lo) | ((unsigned)f2bf(hi) << 16);
}
// load 8 consecutive f32 at p, convert to one bf16x8 A/B fragment
__device__ __forceinline__ bf16x8 ldcvt8(const float* __restrict__ p) {
    const float4 a = *(const float4*)p;
    const float4 b = *(const float4*)(p + 4);
    union { bf16x8 v; uint4 q; } cv;
    cv.q.x = pk2(a.x, a.y); cv.q.y = pk2(a.z, a.w);
    cv.q.z = pk2(b.x, b.y); cv.q.w = pk2(b.z, b.w);
    return cv.v;
}

// ---- K_A: blocks 0..63 EXP-form scl | blocks 64..575 U-build (NO W transpose) ----
// scl: kind0 e^{-v1(i)} | kind1 e^{-(g1(i)+bg_s)} | kind2 e^{-v2(j)} | kind3 e^{-g2(j)}
// U[s][d][j] = sum_e W[s][d][e]*x2[j][e]; stored as Ut[b][s][j][d] (j-major, d contiguous).
__global__ __launch_bounds__(256) void grn_a(
    const float* __restrict__ lstm1, const float* __restrict__ lstm2,
    const float* __restrict__ W, const float* __restrict__ V,
    const float* __restrict__ Wg, const float* __restrict__ bg,
    unsigned char* __restrict__ ws)
{
    __shared__ __align__(16) unsigned short tls[4][16][72];  // per-wave D staging
    float* scl = (float*)(ws + SCL_OFF);
    unsigned short* Ut = (unsigned short*)(ws + U_OFF);
    const int tid = threadIdx.x;
    if (blockIdx.x < 64) {
        const int rb = blockIdx.x;
        const int b = rb >> 3, r0 = (rb & 7) * 64;
        const int kind = tid & 3, row = r0 + (tid >> 2);
        const float* x = (kind < 2 ? lstm1 : lstm2) + ((size_t)b * kL + row) * kD;
        float xr[64];
        #pragma unroll
        for (int q = 0; q < 16; q++)
            *(float4*)&xr[q * 4] = *(const float4*)(x + q * 4);
        const float* vb = ((kind & 1) ? Wg : V) + ((kind & 2) ? kD : 0);
        #pragma unroll
        for (int s = 0; s < kS; s++) {
            const float* vec = vb + s * 2 * kD;
            float a = 0.f;
            #pragma unroll
            for (int q = 0; q < 16; q++) {
                const float4 vv = *(const float4*)(vec + q * 4);
                a = fmaf(vv.x, xr[q * 4 + 0], a);
                a = fmaf(vv.y, xr[q * 4 + 1], a);
                a = fmaf(vv.z, xr[q * 4 + 2], a);
                a = fmaf(vv.w, xr[q * 4 + 3], a);
            }
            const float badd = (kind == 1) ? bg[s] : 0.f;
            scl[(((size_t)kind * 8 + b) * 8 + s) * 512 + row] = __expf(-(a + badd));
        }
        return;
    }
    // ---- U-build: block = (b, s, j64); 4 waves x 16 j-rows x full d; barrier-free ----
    const int t = blockIdx.x - 64;
    const int b = t >> 6, rem = t & 63, s = rem >> 3, j64 = rem & 7;
    const int lane = tid & 63, w = tid >> 6;
    const int fr = lane & 15, fh = lane >> 4;
    const int j0 = j64 * 64 + w * 16;
    // B frags (x2 rows, natural): x2[j0+fr][e-chunk]
    const float* bp = lstm2 + (((size_t)b * kL + j0 + fr) * kD + fh * 8);
    const bf16x8 B0 = ldcvt8(bp);
    const bf16x8 B1 = ldcvt8(bp + 32);
    unsigned short (*__restrict__ tw)[72] = tls[w];
    #pragma unroll
    for (int dt = 0; dt < 4; dt++) {     // A frags (W rows, natural): W[s][dt*16+fr][e-chunk]
        const float* ap = W + ((size_t)s * 4096 + (dt * 16 + fr) * kD + fh * 8);
        const bf16x8 A0 = ldcvt8(ap);
        const bf16x8 A1 = ldcvt8(ap + 32);
        f32x4 z = {0.f, 0.f, 0.f, 0.f};
        f32x4 d = __builtin_amdgcn_mfma_f32_16x16x32_bf16(A0, B0, z, 0, 0, 0);
        d = __builtin_amdgcn_mfma_f32_16x16x32_bf16(A1, B1, d, 0, 0, 0);
        #pragma unroll
        for (int r = 0; r < 4; r++)      // D: col=fr(j), row=fh*4+r(d) -> stage transposed
            tw[fr][dt * 16 + fh * 4 + r] = f2bf(d[r]);
    }
    // read back coalesced (in-wave RAW -> lgkmcnt) and store Ut rows as uint4
    const int rr = lane >> 2, cc = (lane & 3) * 16;
    const uint4 q0 = *(const uint4*)&tw[rr][cc];
    const uint4 q1 = *(const uint4*)&tw[rr][cc + 8];
    unsigned short* up = Ut + (((size_t)(b * 8 + s)) * kL + j0 + rr) * kD + cc;
    *(uint4*)up = q0;
    *(uint4*)(up + 8) = q1;
}

// ---- K_B: one 32x16 output tile per wave; 4096 waves; A(x1) hoisted over s ----
__global__ __launch_bounds__(256) void grn_b(
    const float* __restrict__ lstm1, const float* __restrict__ bS,
    const float* __restrict__ u, const unsigned char* __restrict__ ws,
    float* __restrict__ out)
{
    const float* scl = (const float*)(ws + SCL_OFF);
    const unsigned short* Ut = (const unsigned short*)(ws + U_OFF);
    // XCD swizzle: XCD x owns batch b=x -> its 4.2MB (Ut[b]+x1[b]) set fits private L2
    const int swz = (blockIdx.x & 7) * 128 + (blockIdx.x >> 3);
    const int g = swz * 4 + (threadIdx.x >> 6);          // 0..4095
    const int b = g >> 9, rem = g & 511, i32 = rem >> 5, jt = rem & 31;
    const int lane = threadIdx.x & 63, fr = lane & 15, fh = lane >> 4;
    const int i0 = i32 * 32, j0 = jt * 16;
    // A frags (x1 rows, natural, s-independent): two i16 tiles
    bf16x8 A[2][2];
    #pragma unroll
    for (int ii = 0; ii < 2; ii++) {
        const float* ap = lstm1 + (((size_t)b * kL + i0 + ii * 16 + fr) * kD + fh * 8);
        A[ii][0] = ldcvt8(ap);
        A[ii][1] = ldcvt8(ap + 32);
    }
    float bias_c = 0.f;
    #pragma unroll
    for (int s = 0; s < kS; s++) bias_c = fmaf(u[s], bS[s], bias_c);
    f32x4 oacc[2];
    oacc[0] = f32x4{bias_c, bias_c, bias_c, bias_c};
    oacc[1] = oacc[0];
    #pragma unroll
    for (int s = 0; s < kS; s++) {
        // B frags (Ut rows, natural): Ut[b][s][j0+fr][d-chunk]
        const unsigned short* bp = Ut + (((size_t)(b * 8 + s)) * kL + j0 + fr) * kD + fh * 8;
        const bf16x8 B0 = *(const bf16x8*)bp;
        const bf16x8 B1 = *(const bf16x8*)(bp + 32);
        const float E2v = scl[(((size_t)2 * 8 + b) * 8 + s) * 512 + j0 + fr];
        const float E2g = scl[(((size_t)3 * 8 + b) * 8 + s) * 512 + j0 + fr];
        const float us = u[s];
        #pragma unroll
        for (int ii = 0; ii < 2; ii++) {
            f32x4 z = {0.f, 0.f, 0.f, 0.f};
            f32x4 acc = __builtin_amdgcn_mfma_f32_16x16x32_bf16(A[ii][0], B0, z, 0, 0, 0);
            acc = __builtin_amdgcn_mfma_f32_16x16x32_bf16(A[ii][1], B1, acc, 0, 0, 0);
            const int ib = i0 + ii * 16 + fh * 4;
            const float4 E1vq = *(const float4*)(scl + (((size_t)0 * 8 + b) * 8 + s) * 512 + ib);
            const float4 E1gq = *(const float4*)(scl + (((size_t)1 * 8 + b) * 8 + s) * 512 + ib);
            const float E1va[4] = {E1vq.x, E1vq.y, E1vq.z, E1vq.w};
            const float E1ga[4] = {E1gq.x, E1gq.y, E1gq.z, E1gq.w};
            #pragma unroll
            for (int r = 0; r < 4; r++) {
                const float dg = fmaf(E1ga[r], E2g, 1.f);        // 1 + e^{-(g1+g2+bg)}
                const float dv = fmaf(E1va[r], E2v, 1.f);        // 1 + e^{-(v1+v2)}
                const float rp = __builtin_amdgcn_rcpf(dg * dv); // one rcp, both sigmoids
                const float gate = dv * rp;
                const float sv   = dg * rp;
                const float res = fmaf(gate, acc[r] - sv, sv);   // gate*rw + (1-gate)*sv
                oacc[ii][r] = fmaf(us, res, oacc[ii][r]);
            }
        }
    }
    #pragma unroll
    for (int ii = 0; ii < 2; ii++) {
        float* op = out + (((size_t)b * kL + i0 + ii * 16 + fh * 4) * kL + j0 + fr);
        #pragma unroll
        for (int r = 0; r < 4; r++)      // coalesced 64B segments per row
            op[(size_t)r * kL] = oacc[ii][r];
    }
}

extern "C" void kernel_launch(void* const* d_in, const int* in_sizes, int n_in,
                              void* d_out, int out_size, void* d_ws, size_t ws_size,
                              hipStream_t stream) {
    const float* lstm1 = (const float*)d_in[0];
    const float* lstm2 = (const float*)d_in[1];
    const float* W     = (const float*)d_in[2];
    const float* V     = (const float*)d_in[3];
    const float* bS    = (const float*)d_in[4];
    const float* Wg    = (const float*)d_in[5];
    const float* bg    = (const float*)d_in[6];
    const float* u     = (const float*)d_in[7];
    unsigned char* ws = (unsigned char*)d_ws;   // uses 4.5 MB; ws_size = 256 MiB
    grn_a<<<576, 256, 0, stream>>>(lstm1, lstm2, W, V, Wg, bg, ws);
    grn_b<<<1024, 256, 0, stream>>>(lstm1, bS, u, ws, (float*)d_out);
}

// Round 15
// 102.005 us; speedup vs baseline: 1.0424x; 1.0424x over previous
//
#include <hip/hip_runtime.h>
#include <math.h>

typedef float f32x4 __attribute__((ext_vector_type(4)));
typedef short bf16x8 __attribute__((ext_vector_type(8)));  // 8 bf16 in 4 VGPR

namespace {
constexpr int kB = 8, kL = 512, kD = 64, kS = 8;
// workspace layout (bytes)
constexpr size_t SCL_OFF = 0;                       // f32[4][8][8][512]   = 512 KB
constexpr size_t U_OFF   = 524288;                  // bf16[8][8][512][64] =   4 MB  (Ut[b][s][j][d])
}

__device__ __forceinline__ unsigned short f2bf(float f) {      // RNE float->bf16
    unsigned u = __float_as_uint(f);
    u += 0x7FFFu + ((u >> 16) & 1u);
    return (unsigned short)(u >> 16);
}
__device__ __forceinline__ unsigned pk2(float lo, float hi) {
    return (unsigned)f2bf(lo) | ((unsigned)f2bf(hi) << 16);
}
// load 8 consecutive f32 at p, convert to one bf16x8 A/B fragment
__device__ __forceinline__ bf16x8 ldcvt8(const float* __restrict__ p) {
    const float4 a = *(const float4*)p;
    const float4 b = *(const float4*)(p + 4);
    union { bf16x8 v; uint4 q; } cv;
    cv.q.x = pk2(a.x, a.y); cv.q.y = pk2(a.z, a.w);
    cv.q.z = pk2(b.x, b.y); cv.q.w = pk2(b.z, b.w);
    return cv.v;
}

// ---- K_A: blocks 0..63 EXP-form scl | blocks 64..575 U-build (NO W transpose) ----
// scl: kind0 e^{-v1(i)} | kind1 e^{-(g1(i)+bg_s)} | kind2 e^{-v2(j)} | kind3 e^{-g2(j)}
// U[s][d][j] = sum_e W[s][d][e]*x2[j][e]; stored as Ut[b][s][j][d] (j-major, d contiguous).
__global__ __launch_bounds__(256) void grn_a(
    const float* __restrict__ lstm1, const float* __restrict__ lstm2,
    const float* __restrict__ W, const float* __restrict__ V,
    const float* __restrict__ Wg, const float* __restrict__ bg,
    unsigned char* __restrict__ ws)
{
    __shared__ __align__(16) unsigned short tls[4][16][72];  // per-wave D staging
    float* scl = (float*)(ws + SCL_OFF);
    unsigned short* Ut = (unsigned short*)(ws + U_OFF);
    const int tid = threadIdx.x;
    if (blockIdx.x < 64) {
        const int rb = blockIdx.x;
        const int b = rb >> 3, r0 = (rb & 7) * 64;
        const int kind = tid & 3, row = r0 + (tid >> 2);
        const float* x = (kind < 2 ? lstm1 : lstm2) + ((size_t)b * kL + row) * kD;
        float xr[64];
        #pragma unroll
        for (int q = 0; q < 16; q++)
            *(float4*)&xr[q * 4] = *(const float4*)(x + q * 4);
        const float* vb = ((kind & 1) ? Wg : V) + ((kind & 2) ? kD : 0);
        #pragma unroll
        for (int s = 0; s < kS; s++) {
            const float* vec = vb + s * 2 * kD;
            float a = 0.f;
            #pragma unroll
            for (int q = 0; q < 16; q++) {
                const float4 vv = *(const float4*)(vec + q * 4);
                a = fmaf(vv.x, xr[q * 4 + 0], a);
                a = fmaf(vv.y, xr[q * 4 + 1], a);
                a = fmaf(vv.z, xr[q * 4 + 2], a);
                a = fmaf(vv.w, xr[q * 4 + 3], a);
            }
            const float badd = (kind == 1) ? bg[s] : 0.f;
            scl[(((size_t)kind * 8 + b) * 8 + s) * 512 + row] = __expf(-(a + badd));
        }
        return;
    }
    // ---- U-build: block = (b, s, j64); 4 waves x 16 j-rows x full d; barrier-free ----
    const int t = blockIdx.x - 64;
    const int b = t >> 6, rem = t & 63, s = rem >> 3, j64 = rem & 7;
    const int lane = tid & 63, w = tid >> 6;
    const int fr = lane & 15, fh = lane >> 4;
    const int j0 = j64 * 64 + w * 16;
    // B frags (x2 rows, natural): x2[j0+fr][e-chunk]
    const float* bp = lstm2 + (((size_t)b * kL + j0 + fr) * kD + fh * 8);
    const bf16x8 B0 = ldcvt8(bp);
    const bf16x8 B1 = ldcvt8(bp + 32);
    unsigned short (*__restrict__ tw)[72] = tls[w];
    #pragma unroll
    for (int dt = 0; dt < 4; dt++) {     // A frags (W rows, natural): W[s][dt*16+fr][e-chunk]
        const float* ap = W + ((size_t)s * 4096 + (dt * 16 + fr) * kD + fh * 8);
        const bf16x8 A0 = ldcvt8(ap);
        const bf16x8 A1 = ldcvt8(ap + 32);
        f32x4 z = {0.f, 0.f, 0.f, 0.f};
        f32x4 d = __builtin_amdgcn_mfma_f32_16x16x32_bf16(A0, B0, z, 0, 0, 0);
        d = __builtin_amdgcn_mfma_f32_16x16x32_bf16(A1, B1, d, 0, 0, 0);
        #pragma unroll
        for (int r = 0; r < 4; r++)      // D: col=fr(j), row=fh*4+r(d) -> stage transposed
            tw[fr][dt * 16 + fh * 4 + r] = f2bf(d[r]);
    }
    // read back coalesced (in-wave RAW -> lgkmcnt) and store Ut rows as uint4
    const int rr = lane >> 2, cc = (lane & 3) * 16;
    const uint4 q0 = *(const uint4*)&tw[rr][cc];
    const uint4 q1 = *(const uint4*)&tw[rr][cc + 8];
    unsigned short* up = Ut + (((size_t)(b * 8 + s)) * kL + j0 + rr) * kD + cc;
    *(uint4*)up = q0;
    *(uint4*)(up + 8) = q1;
}

// ---- K_B: one 32x32 output tile per wave; 2048 waves; LDS-bounced 128B stores ----
__global__ __launch_bounds__(256) void grn_b(
    const float* __restrict__ lstm1, const float* __restrict__ bS,
    const float* __restrict__ u, const unsigned char* __restrict__ ws,
    float* __restrict__ out)
{
    __shared__ float ob[4][32][33];   // per-wave out staging, pad 33 to spread banks
    const float* scl = (const float*)(ws + SCL_OFF);
    const unsigned short* Ut = (const unsigned short*)(ws + U_OFF);
    // XCD swizzle: XCD x owns batch b=x -> its ~4.2MB (Ut[b]+x1[b]) set fits private L2
    const int swz = (blockIdx.x & 7) * 64 + (blockIdx.x >> 3);
    const int w = threadIdx.x >> 6;
    const int g = swz * 4 + w;                           // 0..2047
    const int b = g >> 8, rem = g & 255, i32t = rem >> 4, j32t = rem & 15;
    const int lane = threadIdx.x & 63, fr = lane & 15, fh = lane >> 4;
    const int i0 = i32t * 32, j0 = j32t * 32;
    // A frags (x1 rows, natural, s-independent): two i16 tiles
    bf16x8 A[2][2];
    #pragma unroll
    for (int ii = 0; ii < 2; ii++) {
        const float* ap = lstm1 + (((size_t)b * kL + i0 + ii * 16 + fr) * kD + fh * 8);
        A[ii][0] = ldcvt8(ap);
        A[ii][1] = ldcvt8(ap + 32);
    }
    float bias_c = 0.f;
    #pragma unroll
    for (int s = 0; s < kS; s++) bias_c = fmaf(u[s], bS[s], bias_c);
    f32x4 oacc[2][2];
    oacc[0][0] = f32x4{bias_c, bias_c, bias_c, bias_c};
    oacc[0][1] = oacc[0][0]; oacc[1][0] = oacc[0][0]; oacc[1][1] = oacc[0][0];
    #pragma unroll
    for (int s = 0; s < kS; s++) {
        // B frags (Ut rows, natural): two j16 tiles
        const unsigned short* bp = Ut + (((size_t)(b * 8 + s)) * kL + j0 + fr) * kD + fh * 8;
        bf16x8 Bf[2][2];
        #pragma unroll
        for (int jj = 0; jj < 2; jj++) {
            Bf[jj][0] = *(const bf16x8*)(bp + jj * 16 * kD);
            Bf[jj][1] = *(const bf16x8*)(bp + jj * 16 * kD + 32);
        }
        const float us = u[s];
        float E2v[2], E2g[2];
        #pragma unroll
        for (int jj = 0; jj < 2; jj++) {
            E2v[jj] = scl[(((size_t)2 * 8 + b) * 8 + s) * 512 + j0 + jj * 16 + fr];
            E2g[jj] = scl[(((size_t)3 * 8 + b) * 8 + s) * 512 + j0 + jj * 16 + fr];
        }
        #pragma unroll
        for (int ii = 0; ii < 2; ii++) {
            const int ib = i0 + ii * 16 + fh * 4;
            const float4 E1vq = *(const float4*)(scl + (((size_t)0 * 8 + b) * 8 + s) * 512 + ib);
            const float4 E1gq = *(const float4*)(scl + (((size_t)1 * 8 + b) * 8 + s) * 512 + ib);
            const float E1va[4] = {E1vq.x, E1vq.y, E1vq.z, E1vq.w};
            const float E1ga[4] = {E1gq.x, E1gq.y, E1gq.z, E1gq.w};
            #pragma unroll
            for (int jj = 0; jj < 2; jj++) {
                f32x4 z = {0.f, 0.f, 0.f, 0.f};
                f32x4 acc = __builtin_amdgcn_mfma_f32_16x16x32_bf16(A[ii][0], Bf[jj][0], z, 0, 0, 0);
                acc = __builtin_amdgcn_mfma_f32_16x16x32_bf16(A[ii][1], Bf[jj][1], acc, 0, 0, 0);
                #pragma unroll
                for (int r = 0; r < 4; r++) {
                    const float dg = fmaf(E1ga[r], E2g[jj], 1.f);    // 1 + e^{-(g1+g2+bg)}
                    const float dv = fmaf(E1va[r], E2v[jj], 1.f);    // 1 + e^{-(v1+v2)}
                    const float rp = __builtin_amdgcn_rcpf(dg * dv); // one rcp, both sigmoids
                    const float gate = dv * rp;
                    const float sv   = dg * rp;
                    const float res = fmaf(gate, acc[r] - sv, sv);   // gate*rw + (1-gate)*sv
                    oacc[ii][jj][r] = fmaf(us, res, oacc[ii][jj][r]);
                }
            }
        }
    }
    // bounce through LDS (wave-private, in-order DS) -> 128B-contiguous row stores
    float (*__restrict__ ot)[33] = ob[w];
    #pragma unroll
    for (int ii = 0; ii < 2; ii++)
        #pragma unroll
        for (int jj = 0; jj < 2; jj++)
            #pragma unroll
            for (int r = 0; r < 4; r++)
                ot[ii * 16 + fh * 4 + r][jj * 16 + fr] = oacc[ii][jj][r];
    #pragma unroll
    for (int p = 0; p < 4; p++) {        // 1024 floats = 256 float4 = 64 lanes x 4
        const int f = p * 64 + lane;
        const int row = f >> 3, c4 = (f & 7) * 4;
        const float4 v = *(const float4*)&ot[row][c4];
        *(float4*)(out + (((size_t)b * kL + i0 + row) * kL + j0 + c4)) = v;
    }
}

extern "C" void kernel_launch(void* const* d_in, const int* in_sizes, int n_in,
                              void* d_out, int out_size, void* d_ws, size_t ws_size,
                              hipStream_t stream) {
    const float* lstm1 = (const float*)d_in[0];
    const float* lstm2 = (const float*)d_in[1];
    const float* W     = (const float*)d_in[2];
    const float* V     = (const float*)d_in[3];
    const float* bS    = (const float*)d_in[4];
    const float* Wg    = (const float*)d_in[5];
    const float* bg    = (const float*)d_in[6];
    const float* u     = (const float*)d_in[7];
    unsigned char* ws = (unsigned char*)d_ws;   // uses 4.5 MB; ws_size = 256 MiB
    grn_a<<<576, 256, 0, stream>>>(lstm1, lstm2, W, V, Wg, bg, ws);
    grn_b<<<512, 256, 0, stream>>>(lstm1, bS, u, ws, (float*)d_out);
}